// Round 4
// baseline (264.675 us; speedup 1.0000x reference)
//
#include <hip/hip_runtime.h>
#include <math.h>

// Fully-fused 2-layer Mamba-ish block, L=1 => every token independent through
// the WHOLE network. One kernel: each block owns 8 tokens, all intermediates
// in LDS, weights streamed from L2 (3.7MB total, XCD-L2-resident).
// Per layer: LN -> GEMM1(256->1024)+conv/silu -> GEMM2(512->144) -> bc=B.C
//   -> dt=softplus(dtr@dtw+db), y=xc*(dt*bc+D)*silu(gate) -> GEMM3(512->256)+res.
// A_log unused (scan from h0=0, single step).

#define NTOK 3200
#define DM   256
#define DI   512
#define NX   1024
#define DTR  16
#define DS   64
#define NPJ  144
#define TPB  8      // tokens per block
#define THR  512

__device__ __forceinline__ float sigf(float x){ return 1.0f/(1.0f+expf(-x)); }
__device__ __forceinline__ float siluf(float x){ return x*sigf(x); }
__device__ __forceinline__ float softplusf(float x){ return (x>20.f)?x:log1pf(expf(x)); }

__device__ __forceinline__ void fma4(float acc[4], float a, float4 wv){
    acc[0]=fmaf(a, wv.x, acc[0]); acc[1]=fmaf(a, wv.y, acc[1]);
    acc[2]=fmaf(a, wv.z, acc[2]); acc[3]=fmaf(a, wv.w, acc[3]);
}

__global__ __launch_bounds__(THR, 4) void fused_net_kernel(
    const float* __restrict__ x,
    const float* __restrict__ ln_w, const float* __restrict__ ln_b,
    const float* __restrict__ in_w, const float* __restrict__ in_b,
    const float* __restrict__ cw,   const float* __restrict__ cb,
    const float* __restrict__ xw,   const float* __restrict__ dtw,
    const float* __restrict__ dtb,  const float* __restrict__ Dp,
    const float* __restrict__ ow,   const float* __restrict__ ob,
    float* __restrict__ outp)
{
    __shared__ float h [TPB][DM+4];
    __shared__ float xn[TPB][DM+4];
    __shared__ float xc[TPB][DI+4];
    __shared__ float sg[TPB][DI+4];
    __shared__ float dbl[TPB][NPJ+4];
    __shared__ float bcs[TPB];

    const int tid = threadIdx.x;
    const int t0  = blockIdx.x * TPB;

    // ---- load hidden (8 tokens x 256) ----
    {
        const int t = tid>>6, c = (tid&63)*4;
        *(float4*)&h[t][c] = *(const float4*)(x + (size_t)(t0+t)*DM + c);
    }
    __syncthreads();

    for (int l=0; l<2; ++l){
        const float* lw  = ln_w + l*DM;
        const float* lb  = ln_b + l*DM;
        const float* W1  = in_w + (size_t)l*DM*NX;
        const float* b1  = in_b + l*NX;
        const float* cw3 = cw + l*4*DI + 3*DI;   // last conv tap
        const float* cbv = cb + l*DI;
        const float* W2  = xw + (size_t)l*DI*NPJ;
        const float* Wd  = dtw + l*DTR*DI;
        const float* bd  = dtb + l*DI;
        const float* Dv  = Dp + l*DI;
        const float* W3  = ow + (size_t)l*DI*DM;
        const float* b3  = ob + l*DM;

        // ---- LayerNorm: wave w -> token w ----
        {
            const int t = tid>>6, c = (tid&63)*4;
            float4 v = *(float4*)&h[t][c];
            float s = v.x+v.y+v.z+v.w;
            #pragma unroll
            for (int o=32;o>=1;o>>=1) s += __shfl_xor(s, o, 64);
            const float mu = s*(1.0f/DM);
            float4 d = {v.x-mu, v.y-mu, v.z-mu, v.w-mu};
            float q = d.x*d.x+d.y*d.y+d.z*d.z+d.w*d.w;
            #pragma unroll
            for (int o=32;o>=1;o>>=1) q += __shfl_xor(q, o, 64);
            const float r = rsqrtf(q*(1.0f/DM)+1e-5f);
            const float4 w4 = *(const float4*)(lw + c);
            const float4 b4 = *(const float4*)(lb + c);
            float4 o4 = {d.x*r*w4.x+b4.x, d.y*r*w4.y+b4.y,
                         d.z*r*w4.z+b4.z, d.w*r*w4.w+b4.w};
            *(float4*)&xn[t][c] = o4;
        }
        __syncthreads();

        // ---- GEMM1: xn(8x256) @ W1(256x1024); epilogue conv/silu ----
        // group g = tid>>8 owns tokens g*4..g*4+3; slot = tid&255 -> cols slot*4..+3
        {
            const int g = tid>>8;
            const int c0 = (tid&255)*4;
            float acc[4][4] = {};
            #pragma unroll 2
            for (int k0=0;k0<DM;k0+=4){
                const float4 w0 = *(const float4*)(W1 + (size_t)(k0+0)*NX + c0);
                const float4 w1 = *(const float4*)(W1 + (size_t)(k0+1)*NX + c0);
                const float4 w2 = *(const float4*)(W1 + (size_t)(k0+2)*NX + c0);
                const float4 w3 = *(const float4*)(W1 + (size_t)(k0+3)*NX + c0);
                float4 a[4];
                #pragma unroll
                for (int i=0;i<4;i++) a[i] = *(const float4*)&xn[g*4+i][k0];
                #pragma unroll
                for (int i=0;i<4;i++){
                    fma4(acc[i], a[i].x, w0);
                    fma4(acc[i], a[i].y, w1);
                    fma4(acc[i], a[i].z, w2);
                    fma4(acc[i], a[i].w, w3);
                }
            }
            const float4 bv = *(const float4*)(b1 + c0);
            if (c0 < DI){
                const float4 cwv = *(const float4*)(cw3 + c0);
                const float4 cb4 = *(const float4*)(cbv + c0);
                #pragma unroll
                for (int i=0;i<4;i++){
                    const int tt = g*4+i;
                    float4 o;
                    o.x = siluf((acc[i][0]+bv.x)*cwv.x + cb4.x);
                    o.y = siluf((acc[i][1]+bv.y)*cwv.y + cb4.y);
                    o.z = siluf((acc[i][2]+bv.z)*cwv.z + cb4.z);
                    o.w = siluf((acc[i][3]+bv.w)*cwv.w + cb4.w);
                    *(float4*)&xc[tt][c0] = o;
                }
            } else {
                #pragma unroll
                for (int i=0;i<4;i++){
                    const int tt = g*4+i;
                    float4 o;
                    o.x = siluf(acc[i][0]+bv.x);
                    o.y = siluf(acc[i][1]+bv.y);
                    o.z = siluf(acc[i][2]+bv.z);
                    o.w = siluf(acc[i][3]+bv.w);
                    *(float4*)&sg[tt][c0-DI] = o;
                }
            }
        }
        __syncthreads();

        // ---- GEMM2: xc(8x512) @ W2(512x144) -> dbl ----
        if (tid < 288){
            const int t = tid/36, c0 = (tid%36)*4;
            float acc[4] = {};
            #pragma unroll 2
            for (int k0=0;k0<DI;k0+=4){
                const float4 a  = *(const float4*)&xc[t][k0];
                const float4 w0 = *(const float4*)(W2 + (size_t)(k0+0)*NPJ + c0);
                const float4 w1 = *(const float4*)(W2 + (size_t)(k0+1)*NPJ + c0);
                const float4 w2 = *(const float4*)(W2 + (size_t)(k0+2)*NPJ + c0);
                const float4 w3 = *(const float4*)(W2 + (size_t)(k0+3)*NPJ + c0);
                fma4(acc, a.x, w0);
                fma4(acc, a.y, w1);
                fma4(acc, a.z, w2);
                fma4(acc, a.w, w3);
            }
            float4 o = {acc[0],acc[1],acc[2],acc[3]};
            *(float4*)&dbl[t][c0] = o;
        }
        __syncthreads();

        // ---- bc = dot(Bm, Cm) per token ----
        if (tid < 256){
            const int t = tid>>5, lane = tid&31;
            float p = dbl[t][DTR+lane]     * dbl[t][DTR+DS+lane]
                    + dbl[t][DTR+32+lane]  * dbl[t][DTR+DS+32+lane];
            #pragma unroll
            for (int o=16;o>=1;o>>=1) p += __shfl_xor(p, o, 32);
            if (lane==0) bcs[t] = p;
        }
        __syncthreads();

        // ---- dt-projection + elementwise y (in-place into xc) ----
        {
            const int c = tid;   // 512 channels
            float wv[DTR];
            #pragma unroll
            for (int r=0;r<DTR;r++) wv[r] = Wd[r*DI + c];
            const float bdc = bd[c], Dc = Dv[c];
            #pragma unroll
            for (int t=0;t<TPB;t++){
                float dv = bdc;
                #pragma unroll
                for (int r=0;r<DTR;r++) dv = fmaf(dbl[t][r], wv[r], dv);
                dv = softplusf(dv);
                xc[t][c] = xc[t][c]*(dv*bcs[t] + Dc)*sg[t][c];
            }
        }
        __syncthreads();

        // ---- GEMM3: y(8x512) @ W3(512x256) + ob + residual -> h ----
        {
            const int t = tid>>6, c0 = (tid&63)*4;
            float acc[4] = {};
            #pragma unroll 2
            for (int k0=0;k0<DI;k0+=4){
                const float4 a  = *(const float4*)&xc[t][k0];
                const float4 w0 = *(const float4*)(W3 + (size_t)(k0+0)*DM + c0);
                const float4 w1 = *(const float4*)(W3 + (size_t)(k0+1)*DM + c0);
                const float4 w2 = *(const float4*)(W3 + (size_t)(k0+2)*DM + c0);
                const float4 w3 = *(const float4*)(W3 + (size_t)(k0+3)*DM + c0);
                fma4(acc, a.x, w0);
                fma4(acc, a.y, w1);
                fma4(acc, a.z, w2);
                fma4(acc, a.w, w3);
            }
            const float4 bo = *(const float4*)(b3 + c0);
            const float4 rv = *(float4*)&h[t][c0];
            float4 o = {acc[0]+bo.x+rv.x, acc[1]+bo.y+rv.y,
                        acc[2]+bo.z+rv.z, acc[3]+bo.w+rv.w};
            *(float4*)&h[t][c0] = o;   // own element only: no race
        }
        __syncthreads();
    }

    // ---- store final hidden ----
    {
        const int t = tid>>6, c = (tid&63)*4;
        *(float4*)(outp + (size_t)(t0+t)*DM + c) = *(float4*)&h[t][c];
    }
}

extern "C" void kernel_launch(void* const* d_in, const int* in_sizes, int n_in,
                              void* d_out, int out_size, void* d_ws, size_t ws_size,
                              hipStream_t stream)
{
    const float* x    = (const float*)d_in[0];
    const float* ln_w = (const float*)d_in[1];
    const float* ln_b = (const float*)d_in[2];
    const float* in_w = (const float*)d_in[3];
    const float* in_b = (const float*)d_in[4];
    const float* cw   = (const float*)d_in[5];
    const float* cb   = (const float*)d_in[6];
    const float* xw   = (const float*)d_in[7];
    const float* dtw  = (const float*)d_in[8];
    const float* dtb  = (const float*)d_in[9];
    // d_in[10] = A_log: unused (L==1, scan starts at h0=0)
    const float* Dp   = (const float*)d_in[11];
    const float* ow   = (const float*)d_in[12];
    const float* ob   = (const float*)d_in[13];
    float* outp = (float*)d_out;

    fused_net_kernel<<<NTOK/TPB, THR, 0, stream>>>(
        x, ln_w, ln_b, in_w, in_b, cw, cb, xw, dtw, dtb, Dp, ow, ob, outp);
}

// Round 5
// 88.637 us; speedup vs baseline: 2.9861x; 2.9861x over previous
//
#include <hip/hip_runtime.h>
#include <math.h>

// Fully-fused 2-layer Mamba-ish block (L=1 => tokens independent end-to-end).
// MFMA bf16 path: prep kernel packs W1/W2/W3 into B-fragment-layout bf16 in d_ws;
// fused kernel: 16 tokens/block, activations packed to A-fragment layout in LDS.
// mfma_f32_16x16x32_bf16 layouts: A[m][k]: m=lane&15, k=(lane>>4)*8+j
//                                 B[k][n]: n=lane&15, k=(lane>>4)*8+j
//                                 C[r][c]: c=lane&15, r=(lane>>4)*4+reg   (m89-verified)
// A_log unused (single scan step from h0=0).

#define NTOK 3200
#define DM   256
#define DI   512
#define NX   1024
#define DTR  16
#define DS   64
#define NPJ  144
#define TPB  16
#define THR  512

#define PK1 (64*8*64*8)    // W1 packed elements per layer (256x1024)
#define PK2 (9*16*64*8)    // W2 packed (512x144)
#define PK3 (16*16*64*8)   // W3 packed (512x256)

using short8 = __attribute__((ext_vector_type(8))) short;
using f32x4  = __attribute__((ext_vector_type(4))) float;

__device__ __forceinline__ float sigf(float x){ return 1.0f/(1.0f+expf(-x)); }
__device__ __forceinline__ float siluf(float x){ return x*sigf(x); }
__device__ __forceinline__ float softplusf(float x){ return (x>20.f)?x:log1pf(expf(x)); }

__device__ __forceinline__ unsigned short f2bf(float f){
    unsigned int u = __float_as_uint(f);
    u += 0x7FFFu + ((u>>16)&1u);           // round-to-nearest-even
    return (unsigned short)(u>>16);
}
__device__ __forceinline__ float bf2f(unsigned short h){
    return __uint_as_float(((unsigned int)h)<<16);
}
// element index into packed-A LDS [ks][64 lanes][8]
__device__ __forceinline__ int apos(int m, int k){
    return (((k>>5)*64) + (m&15) + (((k&31)>>3)<<4))*8 + (k&7);
}

// ---------------- prep: pack weights to bf16 B-fragment layout ----------------
// frag id per layer: [0,512) W1 (nf=fr>>3, ks=fr&7), [512,656) W2 (f2>>4, f2&15),
// [656,912) W3 (f3>>4, f3&15). thread = (layer, frag, lane).
__global__ __launch_bounds__(256) void prep_kernel(
    const float* __restrict__ in_w, const float* __restrict__ xw,
    const float* __restrict__ ow, unsigned short* __restrict__ ws)
{
    const int gid  = blockIdx.x*256 + threadIdx.x;
    const int lane = gid & 63;
    const int fr   = (gid>>6) % 912;
    const int l    = (gid>>6) / 912;
    const float* src; unsigned short* dst; int N, nf, ks;
    unsigned short* W1p = ws;
    unsigned short* W2p = ws + 2*PK1;
    unsigned short* W3p = ws + 2*PK1 + 2*PK2;
    if (fr < 512){
        src = in_w + (size_t)l*DM*NX; N = NX; nf = fr>>3; ks = fr&7;
        dst = W1p + (size_t)l*PK1 + ((size_t)fr*64 + lane)*8;
    } else if (fr < 656){
        const int f2 = fr-512;
        src = xw + (size_t)l*DI*NPJ; N = NPJ; nf = f2>>4; ks = f2&15;
        dst = W2p + (size_t)l*PK2 + ((size_t)f2*64 + lane)*8;
    } else {
        const int f3 = fr-656;
        src = ow + (size_t)l*DI*DM; N = DM; nf = f3>>4; ks = f3&15;
        dst = W3p + (size_t)l*PK3 + ((size_t)f3*64 + lane)*8;
    }
    const int k0 = ks*32 + (lane>>4)*8;
    const int n  = nf*16 + (lane&15);
    short8 v;
    #pragma unroll
    for (int j=0;j<8;j++) v[j] = (short)f2bf(src[(size_t)(k0+j)*N + n]);
    *(short8*)dst = v;
}

// ---------------- fused network kernel ----------------
__global__ __launch_bounds__(THR) void fused_net_kernel(
    const float* __restrict__ x,
    const float* __restrict__ ln_w, const float* __restrict__ ln_b,
    const float* __restrict__ in_b,
    const float* __restrict__ cw,   const float* __restrict__ cb,
    const float* __restrict__ dtw,  const float* __restrict__ dtb,
    const float* __restrict__ Dp,   const float* __restrict__ ob,
    const unsigned short* __restrict__ wsp,
    float* __restrict__ outp)
{
    __shared__ __align__(16) float h[TPB][DM+4];           // residual fp32
    __shared__ __align__(16) unsigned short xnp[8*64*8];   // A-pack xn (K=256)
    __shared__ __align__(16) unsigned short xcp[16*64*8];  // A-pack xc / y (K=512)
    __shared__ __align__(16) unsigned short sgs[TPB][DI];  // silu(gate) bf16
    __shared__ float dbl[TPB][NPJ+4];
    __shared__ float bcs[TPB];

    const int tid  = threadIdx.x;
    const int lane = tid & 63;
    const int wv   = tid >> 6;
    const int t0   = blockIdx.x * TPB;

    const unsigned short* W1p = wsp;
    const unsigned short* W2p = wsp + 2*PK1;
    const unsigned short* W3p = wsp + 2*PK1 + 2*PK2;

    // ---- load residual tile (16 x 256 fp32) ----
    {
        #pragma unroll
        for (int i=0;i<2;i++){
            const int f4 = tid + i*THR;       // 1024 float4
            const int t = f4>>6, c4 = f4&63;
            *(float4*)&h[t][c4*4] = *(const float4*)(x + (size_t)(t0+t)*DM + c4*4);
        }
    }
    __syncthreads();

    for (int l=0; l<2; ++l){
        const float* lwl = ln_w + l*DM;
        const float* lbl = ln_b + l*DM;
        const float* b1  = in_b + l*NX;
        const float* cw3 = cw + l*4*DI + 3*DI;
        const float* cbv = cb + l*DI;
        const float* dtl = dtw + l*DTR*DI;
        const float* bdl = dtb + l*DI;
        const float* Dl  = Dp + l*DI;
        const float* b3  = ob + l*DM;
        const unsigned short* W1l = W1p + (size_t)l*PK1;
        const unsigned short* W2l = W2p + (size_t)l*PK2;
        const unsigned short* W3l = W3p + (size_t)l*PK3;

        // ---- Phase 1: LayerNorm -> xnp (A-pack bf16) ----
        {
            const int t = tid>>5, q = tid&31, c0 = q*8;
            float4 v0 = *(float4*)&h[t][c0];
            float4 v1 = *(float4*)&h[t][c0+4];
            float s = v0.x+v0.y+v0.z+v0.w + v1.x+v1.y+v1.z+v1.w;
            #pragma unroll
            for (int o=16;o>=1;o>>=1) s += __shfl_xor(s, o, 32);
            const float mu = s*(1.0f/DM);
            float a[8] = {v0.x-mu,v0.y-mu,v0.z-mu,v0.w-mu,
                          v1.x-mu,v1.y-mu,v1.z-mu,v1.w-mu};
            float q2 = 0.f;
            #pragma unroll
            for (int i=0;i<8;i++) q2 += a[i]*a[i];
            #pragma unroll
            for (int o=16;o>=1;o>>=1) q2 += __shfl_xor(q2, o, 32);
            const float r = rsqrtf(q2*(1.0f/DM)+1e-5f);
            #pragma unroll
            for (int i=0;i<8;i++){
                const int c = c0+i;
                const float val = a[i]*r*lwl[c] + lbl[c];
                xnp[apos(t,c)] = f2bf(val);
            }
        }
        __syncthreads();

        // ---- Phase 2: GEMM1 (16x1024, K=256) MFMA; epilogue conv/silu ----
        {
            const int nf0 = wv*8;
            f32x4 acc[8];
            #pragma unroll
            for (int i=0;i<8;i++) acc[i] = f32x4{0.f,0.f,0.f,0.f};
            #pragma unroll
            for (int ks=0;ks<8;ks++){
                const short8 a = *(const short8*)&xnp[(ks*64+lane)*8];
                #pragma unroll
                for (int i=0;i<8;i++){
                    const short8 b = *(const short8*)(W1l + (((size_t)(nf0+i)*8 + ks)*64 + lane)*8);
                    acc[i] = __builtin_amdgcn_mfma_f32_16x16x32_bf16(a, b, acc[i], 0,0,0);
                }
            }
            #pragma unroll
            for (int i=0;i<8;i++){
                const int col = (nf0+i)*16 + (lane&15);
                const float b1v = b1[col];
                if (col < DI){
                    const float cwv = cw3[col], cbb = cbv[col];
                    #pragma unroll
                    for (int r=0;r<4;r++){
                        const int t = (lane>>4)*4 + r;
                        const float xcv = siluf((acc[i][r]+b1v)*cwv + cbb);
                        xcp[apos(t,col)] = f2bf(xcv);
                    }
                } else {
                    #pragma unroll
                    for (int r=0;r<4;r++){
                        const int t = (lane>>4)*4 + r;
                        sgs[t][col-DI] = f2bf(siluf(acc[i][r]+b1v));
                    }
                }
            }
        }
        __syncthreads();

        // ---- Phase 3: GEMM2 (16x144, K=512) MFMA -> dbl (fp32 LDS) ----
        for (int nf = wv; nf < 9; nf += 8){
            f32x4 acc = f32x4{0.f,0.f,0.f,0.f};
            #pragma unroll
            for (int ks=0;ks<16;ks++){
                const short8 a = *(const short8*)&xcp[(ks*64+lane)*8];
                const short8 b = *(const short8*)(W2l + (((size_t)nf*16 + ks)*64 + lane)*8);
                acc = __builtin_amdgcn_mfma_f32_16x16x32_bf16(a, b, acc, 0,0,0);
            }
            const int col = nf*16 + (lane&15);
            #pragma unroll
            for (int r=0;r<4;r++) dbl[(lane>>4)*4 + r][col] = acc[r];
        }
        __syncthreads();

        // ---- Phase 4: bc = dot(Bm,Cm) per token ----
        if (tid < 256){
            const int t = tid>>4, s0 = (tid&15)*4;
            float p = 0.f;
            #pragma unroll
            for (int j=0;j<4;j++)
                p += dbl[t][DTR+s0+j]*dbl[t][DTR+DS+s0+j];
            #pragma unroll
            for (int o=8;o>=1;o>>=1) p += __shfl_xor(p, o, 16);
            if ((tid&15)==0) bcs[t] = p;
        }
        __syncthreads();

        // ---- Phase 5: dt-proj + elementwise y (in-place xcp) ----
        {
            const int c = tid;  // 512 channels
            float wv16[DTR];
            #pragma unroll
            for (int r=0;r<DTR;r++) wv16[r] = dtl[r*DI + c];
            const float bdv = bdl[c], Dv = Dl[c];
            #pragma unroll
            for (int t=0;t<TPB;t++){
                float dv = bdv;
                #pragma unroll
                for (int r=0;r<DTR;r++) dv = fmaf(dbl[t][r], wv16[r], dv);
                dv = softplusf(dv);
                const int ip = apos(t,c);
                const float xcv = bf2f(xcp[ip]);
                const float sgv = bf2f(sgs[t][c]);
                xcp[ip] = f2bf(xcv*(dv*bcs[t] + Dv)*sgv);
            }
        }
        __syncthreads();

        // ---- Phase 6: GEMM3 (16x256, K=512) MFMA + bias + residual -> h ----
        {
            const int nf0 = wv*2;
            f32x4 acc0 = f32x4{0.f,0.f,0.f,0.f};
            f32x4 acc1 = f32x4{0.f,0.f,0.f,0.f};
            #pragma unroll
            for (int ks=0;ks<16;ks++){
                const short8 a = *(const short8*)&xcp[(ks*64+lane)*8];
                const short8 b0 = *(const short8*)(W3l + (((size_t)nf0*16 + ks)*64 + lane)*8);
                const short8 b1v = *(const short8*)(W3l + (((size_t)(nf0+1)*16 + ks)*64 + lane)*8);
                acc0 = __builtin_amdgcn_mfma_f32_16x16x32_bf16(a, b0, acc0, 0,0,0);
                acc1 = __builtin_amdgcn_mfma_f32_16x16x32_bf16(a, b1v, acc1, 0,0,0);
            }
            #pragma unroll
            for (int ni=0;ni<2;ni++){
                const f32x4 acc = ni ? acc1 : acc0;
                const int col = (nf0+ni)*16 + (lane&15);
                const float bo = b3[col];
                #pragma unroll
                for (int r=0;r<4;r++){
                    const int t = (lane>>4)*4 + r;
                    h[t][col] = acc[r] + bo + h[t][col];
                }
            }
        }
        __syncthreads();
    }

    // ---- store final hidden ----
    #pragma unroll
    for (int i=0;i<2;i++){
        const int f4 = tid + i*THR;
        const int t = f4>>6, c4 = f4&63;
        *(float4*)(outp + (size_t)(t0+t)*DM + c4*4) = *(float4*)&h[t][c4*4];
    }
}

extern "C" void kernel_launch(void* const* d_in, const int* in_sizes, int n_in,
                              void* d_out, int out_size, void* d_ws, size_t ws_size,
                              hipStream_t stream)
{
    const float* x    = (const float*)d_in[0];
    const float* ln_w = (const float*)d_in[1];
    const float* ln_b = (const float*)d_in[2];
    const float* in_w = (const float*)d_in[3];
    const float* in_b = (const float*)d_in[4];
    const float* cw   = (const float*)d_in[5];
    const float* cb   = (const float*)d_in[6];
    const float* xw   = (const float*)d_in[7];
    const float* dtw  = (const float*)d_in[8];
    const float* dtb  = (const float*)d_in[9];
    // d_in[10] = A_log: unused (L==1, scan starts at h0=0)
    const float* Dp   = (const float*)d_in[11];
    const float* ow   = (const float*)d_in[12];
    const float* ob   = (const float*)d_in[13];
    float* outp = (float*)d_out;
    unsigned short* wsp = (unsigned short*)d_ws;

    // pack weights (2 layers x 912 frags x 64 lanes = 116736 threads)
    prep_kernel<<<456, 256, 0, stream>>>(in_w, xw, ow, wsp);
    fused_net_kernel<<<NTOK/TPB, THR, 0, stream>>>(
        x, ln_w, ln_b, in_b, cw, cb, dtw, dtb, Dp, ob, wsp, outp);
}

// Round 6
// 69.439 us; speedup vs baseline: 3.8116x; 1.2765x over previous
//
#include <hip/hip_runtime.h>
#include <math.h>

// Fully-fused 2-layer Mamba-ish block (L=1 => tokens independent end-to-end).
// MFMA bf16 path: prep kernel packs W1/W2/W3 into B-fragment-layout bf16 in d_ws;
// fused kernel: 16 tokens/block, activations packed to A-fragment layout in LDS.
// mfma_f32_16x16x32_bf16 layouts: A[m][k]: m=lane&15, k=(lane>>4)*8+j
//                                 B[k][n]: n=lane&15, k=(lane>>4)*8+j
//                                 C[r][c]: c=lane&15, r=(lane>>4)*4+reg   (m89-verified)
// A_log unused (single scan step from h0=0).
// R5 post-mortem: WRITE_SIZE 17.6MB vs 3.2MB output = scratch spill (VGPR capped
// at 128, GEMM1 64 hoisted loads). Fix: launch_bounds(512,1) -> 256 VGPR cap,
// unroll 1 on GEMM1 ks-loop to bound in-flight loads.

#define NTOK 3200
#define DM   256
#define DI   512
#define NX   1024
#define DTR  16
#define DS   64
#define NPJ  144
#define TPB  16
#define THR  512

#define PK1 (64*8*64*8)    // W1 packed elements per layer (256x1024)
#define PK2 (9*16*64*8)    // W2 packed (512x144)
#define PK3 (16*16*64*8)   // W3 packed (512x256)

using short8 = __attribute__((ext_vector_type(8))) short;
using f32x4  = __attribute__((ext_vector_type(4))) float;

__device__ __forceinline__ float sigf(float x){ return 1.0f/(1.0f+expf(-x)); }
__device__ __forceinline__ float siluf(float x){ return x*sigf(x); }
__device__ __forceinline__ float softplusf(float x){ return (x>20.f)?x:log1pf(expf(x)); }

__device__ __forceinline__ unsigned short f2bf(float f){
    unsigned int u = __float_as_uint(f);
    u += 0x7FFFu + ((u>>16)&1u);           // round-to-nearest-even
    return (unsigned short)(u>>16);
}
__device__ __forceinline__ float bf2f(unsigned short h){
    return __uint_as_float(((unsigned int)h)<<16);
}
// element index into packed-A LDS [ks][64 lanes][8]
__device__ __forceinline__ int apos(int m, int k){
    return (((k>>5)*64) + (m&15) + (((k&31)>>3)<<4))*8 + (k&7);
}

// ---------------- prep: pack weights to bf16 B-fragment layout ----------------
__global__ __launch_bounds__(256) void prep_kernel(
    const float* __restrict__ in_w, const float* __restrict__ xw,
    const float* __restrict__ ow, unsigned short* __restrict__ ws)
{
    const int gid  = blockIdx.x*256 + threadIdx.x;
    const int lane = gid & 63;
    const int fr   = (gid>>6) % 912;
    const int l    = (gid>>6) / 912;
    const float* src; unsigned short* dst; int N, nf, ks;
    unsigned short* W1p = ws;
    unsigned short* W2p = ws + 2*PK1;
    unsigned short* W3p = ws + 2*PK1 + 2*PK2;
    if (fr < 512){
        src = in_w + (size_t)l*DM*NX; N = NX; nf = fr>>3; ks = fr&7;
        dst = W1p + (size_t)l*PK1 + ((size_t)fr*64 + lane)*8;
    } else if (fr < 656){
        const int f2 = fr-512;
        src = xw + (size_t)l*DI*NPJ; N = NPJ; nf = f2>>4; ks = f2&15;
        dst = W2p + (size_t)l*PK2 + ((size_t)f2*64 + lane)*8;
    } else {
        const int f3 = fr-656;
        src = ow + (size_t)l*DI*DM; N = DM; nf = f3>>4; ks = f3&15;
        dst = W3p + (size_t)l*PK3 + ((size_t)f3*64 + lane)*8;
    }
    const int k0 = ks*32 + (lane>>4)*8;
    const int n  = nf*16 + (lane&15);
    short8 v;
    #pragma unroll
    for (int j=0;j<8;j++) v[j] = (short)f2bf(src[(size_t)(k0+j)*N + n]);
    *(short8*)dst = v;
}

// ---------------- fused network kernel ----------------
__global__ __launch_bounds__(THR, 1) void fused_net_kernel(
    const float* __restrict__ x,
    const float* __restrict__ ln_w, const float* __restrict__ ln_b,
    const float* __restrict__ in_b,
    const float* __restrict__ cw,   const float* __restrict__ cb,
    const float* __restrict__ dtw,  const float* __restrict__ dtb,
    const float* __restrict__ Dp,   const float* __restrict__ ob,
    const unsigned short* __restrict__ wsp,
    float* __restrict__ outp)
{
    __shared__ __align__(16) float h[TPB][DM+4];           // residual fp32
    __shared__ __align__(16) unsigned short xnp[8*64*8];   // A-pack xn (K=256)
    __shared__ __align__(16) unsigned short xcp[16*64*8];  // A-pack xc / y (K=512)
    __shared__ __align__(16) unsigned short sgs[TPB][DI];  // silu(gate) bf16
    __shared__ float dbl[TPB][NPJ+4];
    __shared__ float bcs[TPB];

    const int tid  = threadIdx.x;
    const int lane = tid & 63;
    const int wv   = tid >> 6;
    const int t0   = blockIdx.x * TPB;

    const unsigned short* W1p = wsp;
    const unsigned short* W2p = wsp + 2*PK1;
    const unsigned short* W3p = wsp + 2*PK1 + 2*PK2;

    // ---- load residual tile (16 x 256 fp32) ----
    {
        #pragma unroll
        for (int i=0;i<2;i++){
            const int f4 = tid + i*THR;       // 1024 float4
            const int t = f4>>6, c4 = f4&63;
            *(float4*)&h[t][c4*4] = *(const float4*)(x + (size_t)(t0+t)*DM + c4*4);
        }
    }
    __syncthreads();

    for (int l=0; l<2; ++l){
        const float* lwl = ln_w + l*DM;
        const float* lbl = ln_b + l*DM;
        const float* b1  = in_b + l*NX;
        const float* cw3 = cw + l*4*DI + 3*DI;
        const float* cbv = cb + l*DI;
        const float* dtl = dtw + l*DTR*DI;
        const float* bdl = dtb + l*DI;
        const float* Dl  = Dp + l*DI;
        const float* b3  = ob + l*DM;
        const unsigned short* W1l = W1p + (size_t)l*PK1;
        const unsigned short* W2l = W2p + (size_t)l*PK2;
        const unsigned short* W3l = W3p + (size_t)l*PK3;

        // ---- Phase 1: LayerNorm -> xnp (A-pack bf16) ----
        {
            const int t = tid>>5, q = tid&31, c0 = q*8;
            float4 v0 = *(float4*)&h[t][c0];
            float4 v1 = *(float4*)&h[t][c0+4];
            float s = v0.x+v0.y+v0.z+v0.w + v1.x+v1.y+v1.z+v1.w;
            #pragma unroll
            for (int o=16;o>=1;o>>=1) s += __shfl_xor(s, o, 32);
            const float mu = s*(1.0f/DM);
            float a[8] = {v0.x-mu,v0.y-mu,v0.z-mu,v0.w-mu,
                          v1.x-mu,v1.y-mu,v1.z-mu,v1.w-mu};
            float q2 = 0.f;
            #pragma unroll
            for (int i=0;i<8;i++) q2 += a[i]*a[i];
            #pragma unroll
            for (int o=16;o>=1;o>>=1) q2 += __shfl_xor(q2, o, 32);
            const float r = rsqrtf(q2*(1.0f/DM)+1e-5f);
            #pragma unroll
            for (int i=0;i<8;i++){
                const int c = c0+i;
                const float val = a[i]*r*lwl[c] + lbl[c];
                xnp[apos(t,c)] = f2bf(val);
            }
        }
        __syncthreads();

        // ---- Phase 2: GEMM1 (16x1024, K=256) MFMA; epilogue conv/silu ----
        {
            const int nf0 = wv*8;
            f32x4 acc[8];
            #pragma unroll
            for (int i=0;i<8;i++) acc[i] = f32x4{0.f,0.f,0.f,0.f};
            #pragma unroll 1
            for (int ks=0;ks<8;ks++){
                const short8 a = *(const short8*)&xnp[(ks*64+lane)*8];
                #pragma unroll
                for (int i=0;i<8;i++){
                    const short8 b = *(const short8*)(W1l + (((size_t)(nf0+i)*8 + ks)*64 + lane)*8);
                    acc[i] = __builtin_amdgcn_mfma_f32_16x16x32_bf16(a, b, acc[i], 0,0,0);
                }
            }
            #pragma unroll
            for (int i=0;i<8;i++){
                const int col = (nf0+i)*16 + (lane&15);
                const float b1v = b1[col];
                if (col < DI){
                    const float cwv = cw3[col], cbb = cbv[col];
                    #pragma unroll
                    for (int r=0;r<4;r++){
                        const int t = (lane>>4)*4 + r;
                        const float xcv = siluf((acc[i][r]+b1v)*cwv + cbb);
                        xcp[apos(t,col)] = f2bf(xcv);
                    }
                } else {
                    #pragma unroll
                    for (int r=0;r<4;r++){
                        const int t = (lane>>4)*4 + r;
                        sgs[t][col-DI] = f2bf(siluf(acc[i][r]+b1v));
                    }
                }
            }
        }
        __syncthreads();

        // ---- Phase 3: GEMM2 (16x144, K=512) MFMA -> dbl (fp32 LDS) ----
        for (int nf = wv; nf < 9; nf += 8){
            f32x4 acc = f32x4{0.f,0.f,0.f,0.f};
            #pragma unroll 4
            for (int ks=0;ks<16;ks++){
                const short8 a = *(const short8*)&xcp[(ks*64+lane)*8];
                const short8 b = *(const short8*)(W2l + (((size_t)nf*16 + ks)*64 + lane)*8);
                acc = __builtin_amdgcn_mfma_f32_16x16x32_bf16(a, b, acc, 0,0,0);
            }
            const int col = nf*16 + (lane&15);
            #pragma unroll
            for (int r=0;r<4;r++) dbl[(lane>>4)*4 + r][col] = acc[r];
        }
        __syncthreads();

        // ---- Phase 4: bc = dot(Bm,Cm) per token ----
        if (tid < 256){
            const int t = tid>>4, s0 = (tid&15)*4;
            float p = 0.f;
            #pragma unroll
            for (int j=0;j<4;j++)
                p += dbl[t][DTR+s0+j]*dbl[t][DTR+DS+s0+j];
            #pragma unroll
            for (int o=8;o>=1;o>>=1) p += __shfl_xor(p, o, 16);
            if ((tid&15)==0) bcs[t] = p;
        }
        __syncthreads();

        // ---- Phase 5: dt-proj + elementwise y (in-place xcp) ----
        {
            const int c = tid;  // 512 channels
            float wv16[DTR];
            #pragma unroll
            for (int r=0;r<DTR;r++) wv16[r] = dtl[r*DI + c];
            const float bdv = bdl[c], Dv = Dl[c];
            #pragma unroll
            for (int t=0;t<TPB;t++){
                float dv = bdv;
                #pragma unroll
                for (int r=0;r<DTR;r++) dv = fmaf(dbl[t][r], wv16[r], dv);
                dv = softplusf(dv);
                const int ip = apos(t,c);
                const float xcv = bf2f(xcp[ip]);
                const float sgv = bf2f(sgs[t][c]);
                xcp[ip] = f2bf(xcv*(dv*bcs[t] + Dv)*sgv);
            }
        }
        __syncthreads();

        // ---- Phase 6: GEMM3 (16x256, K=512) MFMA + bias + residual -> h ----
        {
            const int nf0 = wv*2;
            f32x4 acc0 = f32x4{0.f,0.f,0.f,0.f};
            f32x4 acc1 = f32x4{0.f,0.f,0.f,0.f};
            #pragma unroll 4
            for (int ks=0;ks<16;ks++){
                const short8 a = *(const short8*)&xcp[(ks*64+lane)*8];
                const short8 b0 = *(const short8*)(W3l + (((size_t)nf0*16 + ks)*64 + lane)*8);
                const short8 b1v = *(const short8*)(W3l + (((size_t)(nf0+1)*16 + ks)*64 + lane)*8);
                acc0 = __builtin_amdgcn_mfma_f32_16x16x32_bf16(a, b0, acc0, 0,0,0);
                acc1 = __builtin_amdgcn_mfma_f32_16x16x32_bf16(a, b1v, acc1, 0,0,0);
            }
            #pragma unroll
            for (int ni=0;ni<2;ni++){
                const f32x4 acc = ni ? acc1 : acc0;
                const int col = (nf0+ni)*16 + (lane&15);
                const float bo = b3[col];
                #pragma unroll
                for (int r=0;r<4;r++){
                    const int t = (lane>>4)*4 + r;
                    h[t][col] = acc[r] + bo + h[t][col];
                }
            }
        }
        __syncthreads();
    }

    // ---- store final hidden ----
    #pragma unroll
    for (int i=0;i<2;i++){
        const int f4 = tid + i*THR;
        const int t = f4>>6, c4 = f4&63;
        *(float4*)(outp + (size_t)(t0+t)*DM + c4*4) = *(float4*)&h[t][c4*4];
    }
}

extern "C" void kernel_launch(void* const* d_in, const int* in_sizes, int n_in,
                              void* d_out, int out_size, void* d_ws, size_t ws_size,
                              hipStream_t stream)
{
    const float* x    = (const float*)d_in[0];
    const float* ln_w = (const float*)d_in[1];
    const float* ln_b = (const float*)d_in[2];
    const float* in_w = (const float*)d_in[3];
    const float* in_b = (const float*)d_in[4];
    const float* cw   = (const float*)d_in[5];
    const float* cb   = (const float*)d_in[6];
    const float* xw   = (const float*)d_in[7];
    const float* dtw  = (const float*)d_in[8];
    const float* dtb  = (const float*)d_in[9];
    // d_in[10] = A_log: unused (L==1, scan starts at h0=0)
    const float* Dp   = (const float*)d_in[11];
    const float* ow   = (const float*)d_in[12];
    const float* ob   = (const float*)d_in[13];
    float* outp = (float*)d_out;
    unsigned short* wsp = (unsigned short*)d_ws;

    // pack weights (2 layers x 912 frags x 64 lanes = 116736 threads)
    prep_kernel<<<456, 256, 0, stream>>>(in_w, xw, ow, wsp);
    fused_net_kernel<<<NTOK/TPB, THR, 0, stream>>>(
        x, ln_w, ln_b, in_b, cw, cb, dtw, dtb, Dp, ob, wsp, outp);
}

// Round 7
// 53.613 us; speedup vs baseline: 4.9368x; 1.2952x over previous
//
#include <hip/hip_runtime.h>
#include <math.h>

// Fully-fused 2-layer Mamba-ish block (L=1 => tokens independent end-to-end).
// MFMA bf16 path: prep kernel packs W1/W2/W3/W4(dtproj) into B-fragment-layout
// bf16 in d_ws; fused kernel: 16 tokens/block, activations A-packed in LDS.
// mfma_f32_16x16x32_bf16: A[m][k]: m=lane&15, k=(lane>>4)*8+j
//                         B[k][n]: n=lane&15, k=(lane>>4)*8+j
//                         C[r][c]: c=lane&15, r=(lane>>4)*4+reg   (m89-verified)
// A_log unused (single scan step from h0=0).
// R5 post-mortem: WRITE_SIZE 17.6MB = scratch spill -> launch_bounds(512,1)+unroll 1.
// R6 post-mortem: VALU-heavy (dt-proj 256 FMA/thread + slow softplus/silu) and
//   L2-latency-stalled (8 loads in flight). Fix: dt-proj on MFMA (W4 pack),
//   fast __expf/__logf/rcp transcendentals, unroll 2/8/4 on GEMM ks-loops.

#define NTOK 3200
#define DM   256
#define DI   512
#define NX   1024
#define DTR  16
#define DS   64
#define NPJ  144
#define TPB  16
#define THR  512

#define PK1 (64*8*64*8)    // W1 packed elems/layer (256x1024)
#define PK2 (9*16*64*8)    // W2 (512x144)
#define PK3 (16*16*64*8)   // W3 (512x256)
#define PK4 (32*64*8)      // W4 dtproj (16x512, K zero-padded to 32)

using short8 = __attribute__((ext_vector_type(8))) short;
using f32x4  = __attribute__((ext_vector_type(4))) float;

__device__ __forceinline__ float siluf(float x){
    return x * __builtin_amdgcn_rcpf(1.0f + __expf(-x));
}
__device__ __forceinline__ float softplusf(float x){
    return (x > 15.f) ? x : __logf(1.0f + __expf(x));
}

__device__ __forceinline__ unsigned short f2bf(float f){
    unsigned int u = __float_as_uint(f);
    u += 0x7FFFu + ((u>>16)&1u);           // RNE
    return (unsigned short)(u>>16);
}
__device__ __forceinline__ float bf2f(unsigned short h){
    return __uint_as_float(((unsigned int)h)<<16);
}
// element index into packed-A LDS [ks][64 lanes][8]
__device__ __forceinline__ int apos(int m, int k){
    return (((k>>5)*64) + (m&15) + (((k&31)>>3)<<4))*8 + (k&7);
}

// ---------------- prep: pack weights to bf16 B-fragment layout ----------------
// frags/layer: [0,512) W1, [512,656) W2, [656,912) W3, [912,944) W4.
__global__ __launch_bounds__(256) void prep_kernel(
    const float* __restrict__ in_w, const float* __restrict__ xw,
    const float* __restrict__ ow,   const float* __restrict__ dtw,
    unsigned short* __restrict__ ws)
{
    const int gid  = blockIdx.x*256 + threadIdx.x;
    const int lane = gid & 63;
    const int fr   = (gid>>6) % 944;
    const int l    = (gid>>6) / 944;
    unsigned short* W1p = ws;
    unsigned short* W2p = ws + 2*PK1;
    unsigned short* W3p = ws + 2*PK1 + 2*PK2;
    unsigned short* W4p = ws + 2*PK1 + 2*PK2 + 2*PK3;

    if (fr >= 912){   // W4: dtproj, K=16 zero-padded to 32
        const int nf = fr - 912;
        const float* src = dtw + (size_t)l*DTR*DI;
        const int n = nf*16 + (lane&15);
        short8 v;
        #pragma unroll
        for (int j=0;j<8;j++){
            const int k = (lane>>4)*8 + j;
            v[j] = (k < DTR) ? (short)f2bf(src[(size_t)k*DI + n]) : (short)0;
        }
        *(short8*)(W4p + (size_t)l*PK4 + ((size_t)nf*64 + lane)*8) = v;
        return;
    }
    const float* src; unsigned short* dst; int N, nf, ks;
    if (fr < 512){
        src = in_w + (size_t)l*DM*NX; N = NX; nf = fr>>3; ks = fr&7;
        dst = W1p + (size_t)l*PK1 + ((size_t)fr*64 + lane)*8;
    } else if (fr < 656){
        const int f2 = fr-512;
        src = xw + (size_t)l*DI*NPJ; N = NPJ; nf = f2>>4; ks = f2&15;
        dst = W2p + (size_t)l*PK2 + ((size_t)f2*64 + lane)*8;
    } else {
        const int f3 = fr-656;
        src = ow + (size_t)l*DI*DM; N = DM; nf = f3>>4; ks = f3&15;
        dst = W3p + (size_t)l*PK3 + ((size_t)f3*64 + lane)*8;
    }
    const int k0 = ks*32 + (lane>>4)*8;
    const int n  = nf*16 + (lane&15);
    short8 v;
    #pragma unroll
    for (int j=0;j<8;j++) v[j] = (short)f2bf(src[(size_t)(k0+j)*N + n]);
    *(short8*)dst = v;
}

// ---------------- fused network kernel ----------------
__global__ __launch_bounds__(THR, 1) void fused_net_kernel(
    const float* __restrict__ x,
    const float* __restrict__ ln_w, const float* __restrict__ ln_b,
    const float* __restrict__ in_b,
    const float* __restrict__ cw,   const float* __restrict__ cb,
    const float* __restrict__ dtb,
    const float* __restrict__ Dp,   const float* __restrict__ ob,
    const unsigned short* __restrict__ wsp,
    float* __restrict__ outp)
{
    __shared__ __align__(16) float h[TPB][DM+4];           // residual fp32
    __shared__ __align__(16) unsigned short xnp[8*64*8];   // A-pack xn (K=256)
    __shared__ __align__(16) unsigned short xcp[16*64*8];  // A-pack xc / y (K=512)
    __shared__ __align__(16) unsigned short sgs[TPB][DI];  // silu(gate) bf16
    __shared__ float dbl[TPB][NPJ+4];
    __shared__ float bcs[TPB];

    const int tid  = threadIdx.x;
    const int lane = tid & 63;
    const int wv   = tid >> 6;
    const int t0   = blockIdx.x * TPB;

    const unsigned short* W1p = wsp;
    const unsigned short* W2p = wsp + 2*PK1;
    const unsigned short* W3p = wsp + 2*PK1 + 2*PK2;
    const unsigned short* W4p = wsp + 2*PK1 + 2*PK2 + 2*PK3;

    // ---- load residual tile (16 x 256 fp32) ----
    #pragma unroll
    for (int i=0;i<2;i++){
        const int f4 = tid + i*THR;
        const int t = f4>>6, c4 = f4&63;
        *(float4*)&h[t][c4*4] = *(const float4*)(x + (size_t)(t0+t)*DM + c4*4);
    }
    __syncthreads();

    for (int l=0; l<2; ++l){
        const float* lwl = ln_w + l*DM;
        const float* lbl = ln_b + l*DM;
        const float* b1  = in_b + l*NX;
        const float* cw3 = cw + l*4*DI + 3*DI;
        const float* cbv = cb + l*DI;
        const float* bdl = dtb + l*DI;
        const float* Dl  = Dp + l*DI;
        const float* b3  = ob + l*DM;
        const unsigned short* W1l = W1p + (size_t)l*PK1;
        const unsigned short* W2l = W2p + (size_t)l*PK2;
        const unsigned short* W3l = W3p + (size_t)l*PK3;
        const unsigned short* W4l = W4p + (size_t)l*PK4;

        // ---- Phase 1: LayerNorm -> xnp (A-pack bf16) ----
        {
            const int t = tid>>5, q = tid&31, c0 = q*8;
            float4 v0 = *(float4*)&h[t][c0];
            float4 v1 = *(float4*)&h[t][c0+4];
            float s = v0.x+v0.y+v0.z+v0.w + v1.x+v1.y+v1.z+v1.w;
            #pragma unroll
            for (int o=16;o>=1;o>>=1) s += __shfl_xor(s, o, 32);
            const float mu = s*(1.0f/DM);
            float a[8] = {v0.x-mu,v0.y-mu,v0.z-mu,v0.w-mu,
                          v1.x-mu,v1.y-mu,v1.z-mu,v1.w-mu};
            float q2 = 0.f;
            #pragma unroll
            for (int i=0;i<8;i++) q2 += a[i]*a[i];
            #pragma unroll
            for (int o=16;o>=1;o>>=1) q2 += __shfl_xor(q2, o, 32);
            const float r = rsqrtf(q2*(1.0f/DM)+1e-5f);
            #pragma unroll
            for (int i=0;i<8;i++){
                const int c = c0+i;
                xnp[apos(t,c)] = f2bf(a[i]*r*lwl[c] + lbl[c]);
            }
        }
        __syncthreads();

        // ---- Phase 2: GEMM1 (16x1024, K=256) MFMA; epilogue conv/silu ----
        {
            const int nf0 = wv*8;
            f32x4 acc[8];
            #pragma unroll
            for (int i=0;i<8;i++) acc[i] = f32x4{0.f,0.f,0.f,0.f};
            #pragma unroll 2
            for (int ks=0;ks<8;ks++){
                const short8 a = *(const short8*)&xnp[(ks*64+lane)*8];
                #pragma unroll
                for (int i=0;i<8;i++){
                    const short8 b = *(const short8*)(W1l + (((size_t)(nf0+i)*8 + ks)*64 + lane)*8);
                    acc[i] = __builtin_amdgcn_mfma_f32_16x16x32_bf16(a, b, acc[i], 0,0,0);
                }
            }
            #pragma unroll
            for (int i=0;i<8;i++){
                const int col = (nf0+i)*16 + (lane&15);
                const float b1v = b1[col];
                if (col < DI){
                    const float cwv = cw3[col], cbb = cbv[col];
                    #pragma unroll
                    for (int r=0;r<4;r++){
                        const int t = (lane>>4)*4 + r;
                        xcp[apos(t,col)] = f2bf(siluf((acc[i][r]+b1v)*cwv + cbb));
                    }
                } else {
                    #pragma unroll
                    for (int r=0;r<4;r++){
                        const int t = (lane>>4)*4 + r;
                        sgs[t][col-DI] = f2bf(siluf(acc[i][r]+b1v));
                    }
                }
            }
        }
        __syncthreads();

        // ---- Phase 3: GEMM2 (16x144, K=512) MFMA -> dbl (fp32 LDS) ----
        for (int nf = wv; nf < 9; nf += 8){
            f32x4 acc = f32x4{0.f,0.f,0.f,0.f};
            #pragma unroll 8
            for (int ks=0;ks<16;ks++){
                const short8 a = *(const short8*)&xcp[(ks*64+lane)*8];
                const short8 b = *(const short8*)(W2l + (((size_t)nf*16 + ks)*64 + lane)*8);
                acc = __builtin_amdgcn_mfma_f32_16x16x32_bf16(a, b, acc, 0,0,0);
            }
            const int col = nf*16 + (lane&15);
            #pragma unroll
            for (int r=0;r<4;r++) dbl[(lane>>4)*4 + r][col] = acc[r];
        }
        __syncthreads();

        // ---- Phase 4: bc = dot(Bm,Cm) per token ----
        if (tid < 256){
            const int t = tid>>4, s0 = (tid&15)*4;
            float p = 0.f;
            #pragma unroll
            for (int j=0;j<4;j++)
                p += dbl[t][DTR+s0+j]*dbl[t][DTR+DS+s0+j];
            #pragma unroll
            for (int o=8;o>=1;o>>=1) p += __shfl_xor(p, o, 16);
            if ((tid&15)==0) bcs[t] = p;
        }
        __syncthreads();

        // ---- Phase 5: dt-proj via MFMA + elementwise y (in-place xcp) ----
        {
            // A-frag from dbl[:, 0:16] (K=16, zero-pad to 32); same for all nf.
            short8 a;
            const int m = lane&15, kg = lane>>4;
            #pragma unroll
            for (int j=0;j<8;j++){
                const int k = kg*8 + j;
                a[j] = (k < DTR) ? (short)f2bf(dbl[m][k]) : (short)0;
            }
            #pragma unroll
            for (int i=0;i<4;i++){
                const int nf = wv*4 + i;
                const short8 b = *(const short8*)(W4l + ((size_t)nf*64 + lane)*8);
                f32x4 acc = f32x4{0.f,0.f,0.f,0.f};
                acc = __builtin_amdgcn_mfma_f32_16x16x32_bf16(a, b, acc, 0,0,0);
                const int c = nf*16 + (lane&15);
                const float bdv = bdl[c], Dv = Dl[c];
                #pragma unroll
                for (int r=0;r<4;r++){
                    const int t = kg*4 + r;
                    const float dtv = softplusf(acc[r] + bdv);
                    const int ip = apos(t,c);
                    const float yv = bf2f(xcp[ip])*(dtv*bcs[t] + Dv)*bf2f(sgs[t][c]);
                    xcp[ip] = f2bf(yv);
                }
            }
        }
        __syncthreads();

        // ---- Phase 6: GEMM3 (16x256, K=512) MFMA + bias + residual -> h ----
        {
            const int nf0 = wv*2;
            f32x4 acc0 = f32x4{0.f,0.f,0.f,0.f};
            f32x4 acc1 = f32x4{0.f,0.f,0.f,0.f};
            #pragma unroll 4
            for (int ks=0;ks<16;ks++){
                const short8 a = *(const short8*)&xcp[(ks*64+lane)*8];
                const short8 b0 = *(const short8*)(W3l + (((size_t)nf0*16 + ks)*64 + lane)*8);
                const short8 b1v = *(const short8*)(W3l + (((size_t)(nf0+1)*16 + ks)*64 + lane)*8);
                acc0 = __builtin_amdgcn_mfma_f32_16x16x32_bf16(a, b0, acc0, 0,0,0);
                acc1 = __builtin_amdgcn_mfma_f32_16x16x32_bf16(a, b1v, acc1, 0,0,0);
            }
            #pragma unroll
            for (int ni=0;ni<2;ni++){
                const f32x4 acc = ni ? acc1 : acc0;
                const int col = (nf0+ni)*16 + (lane&15);
                const float bo = b3[col];
                #pragma unroll
                for (int r=0;r<4;r++){
                    const int t = (lane>>4)*4 + r;
                    h[t][col] = acc[r] + bo + h[t][col];
                }
            }
        }
        __syncthreads();
    }

    // ---- store final hidden ----
    #pragma unroll
    for (int i=0;i<2;i++){
        const int f4 = tid + i*THR;
        const int t = f4>>6, c4 = f4&63;
        *(float4*)(outp + (size_t)(t0+t)*DM + c4*4) = *(float4*)&h[t][c4*4];
    }
}

extern "C" void kernel_launch(void* const* d_in, const int* in_sizes, int n_in,
                              void* d_out, int out_size, void* d_ws, size_t ws_size,
                              hipStream_t stream)
{
    const float* x    = (const float*)d_in[0];
    const float* ln_w = (const float*)d_in[1];
    const float* ln_b = (const float*)d_in[2];
    const float* in_w = (const float*)d_in[3];
    const float* in_b = (const float*)d_in[4];
    const float* cw   = (const float*)d_in[5];
    const float* cb   = (const float*)d_in[6];
    const float* xw   = (const float*)d_in[7];
    const float* dtw  = (const float*)d_in[8];
    const float* dtb  = (const float*)d_in[9];
    // d_in[10] = A_log: unused (L==1, scan starts at h0=0)
    const float* Dp   = (const float*)d_in[11];
    const float* ow   = (const float*)d_in[12];
    const float* ob   = (const float*)d_in[13];
    float* outp = (float*)d_out;
    unsigned short* wsp = (unsigned short*)d_ws;

    // pack weights: 2 layers x 944 frags x 64 lanes = 120832 threads
    prep_kernel<<<472, 256, 0, stream>>>(in_w, xw, ow, dtw, wsp);
    fused_net_kernel<<<NTOK/TPB, THR, 0, stream>>>(
        x, ln_w, ln_b, in_b, cw, cb, dtb, Dp, ob, wsp, outp);
}